// Round 3
// baseline (182.209 us; speedup 1.0000x reference)
//
#include <hip/hip_runtime.h>

// Problem constants: B=16, L=1024, K=8, N=64, Hh=64
#define NBL 16384

// workspace float offsets
#define WS_HPOW 0            // [NBL][8]
#define WS_YSUM 131072       // [NBL]
#define WS_AVG  147456       // [B][K]
#define WS_WP   147584       // packed head weights [64][16]
#define WS_BP   148608       // packed head biases [16]

// output float offsets
#define OFF_V  0
#define OFF_H  262144
#define OFF_Y  17039360
#define OFF_BT 19136512
#define OFF_BY 19267584
#define OFF_BH 19398656
#define OFF_BD 19529728

// ---------------------------------------------------------------- kernel A
// per (b,l): h_power[k], y_sum; block 0 also packs head weights into ws
__global__ __launch_bounds__(256) void k_power(const float* __restrict__ Hm,
                                               const float* __restrict__ ym,
                                               const float* __restrict__ Wy,
                                               const float* __restrict__ By,
                                               const float* __restrict__ Wh,
                                               const float* __restrict__ Bh,
                                               const float* __restrict__ Wd,
                                               const float* __restrict__ Bd,
                                               float* __restrict__ ws) {
  const int bl = blockIdx.x;
  const int t  = threadIdx.x;
  __shared__ float wsum[4][8];
  float4 h4 = *(const float4*)(Hm + bl * 1024 + t * 4);
  float s0 = h4.x * h4.x + h4.y * h4.y;
  float s1 = h4.z * h4.z + h4.w * h4.w;
  #pragma unroll
  for (int m = 4; m <= 32; m <<= 1) {
    s0 += __shfl_xor(s0, m, 64);
    s1 += __shfl_xor(s1, m, 64);
  }
  const int lane = t & 63, w = t >> 6;
  if (lane < 4) {
    wsum[w][2 * lane]     = s0;
    wsum[w][2 * lane + 1] = s1;
  }
  __syncthreads();
  if (t < 8)
    ws[WS_HPOW + bl * 8 + t] = wsum[0][t] + wsum[1][t] + wsum[2][t] + wsum[3][t];
  if (t >= 64 && t < 128) {   // wave 1: y power
    const int u = t - 64;
    float p = 0.0f;
    if (u < 32) {
      float4 v4 = *(const float4*)(ym + bl * 128 + u * 4);
      p = v4.x * v4.x + v4.y * v4.y + v4.z * v4.z + v4.w * v4.w;
    }
    #pragma unroll
    for (int m = 1; m <= 32; m <<= 1) p += __shfl_xor(p, m, 64);
    if (u == 0) ws[WS_YSUM + bl] = p;
  }
  if (blockIdx.x == 0 && t >= 128 && t < 192) {  // wave 2: pack head weights
    const int ic = t - 128;
    #pragma unroll
    for (int m = 0; m < 5; m++) {
      ws[WS_WP + ic * 16 + m]      = Wy[ic * 5 + m];
      ws[WS_WP + ic * 16 + 5 + m]  = Wh[ic * 5 + m];
      ws[WS_WP + ic * 16 + 10 + m] = Wd[ic * 5 + m];
    }
    ws[WS_WP + ic * 16 + 15] = 0.0f;
    if (ic < 5) {
      ws[WS_BP + ic]      = By[ic];
      ws[WS_BP + 5 + ic]  = Bh[ic];
      ws[WS_BP + 10 + ic] = Bd[ic];
    }
    if (ic == 5) ws[WS_BP + 15] = 0.0f;
  }
}

// ---------------------------------------------------------------- kernel B
__global__ __launch_bounds__(256) void k_avg(float* __restrict__ ws) {
  const int bk = blockIdx.x;
  const int b = bk >> 3, k = bk & 7;
  const int t = threadIdx.x;
  __shared__ float red[256];
  float p = 0.0f;
  for (int l = t; l < 1024; l += 256)
    p += ws[WS_HPOW + ((b << 10) + l) * 8 + k];
  red[t] = p;
  __syncthreads();
  for (int st = 128; st > 0; st >>= 1) {
    if (t < st) red[t] += red[t + st];
    __syncthreads();
  }
  if (t == 0) ws[WS_AVG + bk] = red[0] * (1.0f / 1024.0f);
}

// ---------------------------------------------------------------- helpers
// one MLP layer: acts in this lane's LDS row (stride 65), acc[64] in VGPRs,
// weights fetched wave-uniform (readfirstlane -> s_load, SGPR FMA operand)
template <int NIC>
__device__ __forceinline__ void layerN(const float* __restrict__ Wg,
                                       const float* __restrict__ Bg,
                                       float* __restrict__ arow) {
  float acc[64];
  #pragma unroll
  for (int j = 0; j < 64; j++) acc[j] = Bg[j];
  #pragma unroll 2
  for (int ic = 0; ic < NIC; ++ic) {
    const int icu = __builtin_amdgcn_readfirstlane(ic);
    const float a = arow[icu];
    const float* wr = Wg + icu * 64;
    #pragma unroll
    for (int j = 0; j < 64; j++) acc[j] = fmaf(a, wr[j], acc[j]);
  }
  #pragma unroll
  for (int j = 0; j < 64; j++) arow[j] = fmaxf(acc[j], 0.0f);
}

// LSQ params for chosen branch j; j==0 encodes the zero branch
__device__ __forceinline__ void qparams(int j, const float* __restrict__ sv,
                                        double fsize, float& se, float& qn,
                                        float& qp) {
  se = 1.0f; qn = 0.0f; qp = 0.0f;
  if (j > 0) {
    const int p = 1 << (4 * j - 1);            // 8,128,2048,32768
    const float gscale = (float)(1.0 / sqrt(fsize * (double)(p - 1)));
    const float s  = sv[j - 1];
    const float sg = s * gscale;
    se = sg + (s - sg);                        // literal forward of s_eff
    qn = -(float)p; qp = (float)(p - 1);
  }
}

__device__ __forceinline__ float quantv(float x, float seff, float qn, float qp) {
  float xs = fminf(fmaxf(x / seff, qn), qp);   // exact IEEE div, matches ref
  float r  = rintf(xs);                        // round half-even == jnp.round
  return (xs + (r - xs)) * seff;
}

// ---------------------------------------------------------------- kernel C
// one site per lane; wave = 8 (b,l) pairs; weights via scalar pipe
__global__ __launch_bounds__(256, 2) void k_main(
    const float* __restrict__ v,  const float* __restrict__ Hm,
    const float* __restrict__ ym, const float* __restrict__ snr,
    const float* __restrict__ gy, const float* __restrict__ gH,
    const float* __restrict__ gd,
    const float* __restrict__ W1, const float* __restrict__ B1,
    const float* __restrict__ W2, const float* __restrict__ B2,
    const float* __restrict__ W3, const float* __restrict__ B3,
    const float* __restrict__ sy, const float* __restrict__ sH,
    const float* __restrict__ sd,
    const float* __restrict__ ws, float* __restrict__ out) {

  __shared__ __align__(16) float act[4][64][65];  // [wave][site][ic] row stride 65
  __shared__ __align__(16) float qh[4][8][8][4];  // [wave][slot][k]{se,qn,qp,-}

  const int t    = threadIdx.x;
  const int w    = t >> 6;
  const int lane = t & 63;
  const int s    = lane >> 3;        // bl slot within wave
  const int k    = lane & 7;
  const int blw  = blockIdx.x * 32 + w * 8;
  const int bl   = blw + s;
  float* arow = &act[w][lane][0];

  // ---- features (per lane, straight into own LDS act row)
  float tot = 0.0f;
  #pragma unroll
  for (int kk = 0; kk < 8; kk++) tot += ws[WS_HPOW + bl * 8 + kk];
  const float hp = ws[WS_HPOW + bl * 8 + k];
  const float vr = v[bl * 16 + 2 * k], vi = v[bl * 16 + 2 * k + 1];
  arow[0] = vr;
  arow[1] = vi;
  arow[2] = snr[bl * 8 + k];
  arow[3] = hp;
  arow[4] = ws[WS_AVG + (bl >> 10) * 8 + k];
  arow[5] = log1pf(hp / (tot - hp + 1e-10f));
  arow[6] = log1pf(tot);
  arow[7] = log1pf(ws[WS_YSUM + bl]);
  arow[8] = sqrtf(vr * vr + vi * vi + 1e-10f);

  // ---- MLP (weights through scalar pipe, acts in own LDS row)
  layerN<9>(W1, B1, arow);
  layerN<64>(W2, B2, arow);
  layerN<64>(W3, B3, arow);

  // ---- heads: 15 logits, packed weights ws[WS_WP + ic*16 + m]
  float ho[15];
  #pragma unroll
  for (int m = 0; m < 15; m++) ho[m] = ws[WS_BP + m];
  #pragma unroll 2
  for (int ic = 0; ic < 64; ++ic) {
    const int icu = __builtin_amdgcn_readfirstlane(ic);
    const float a = arow[icu];
    const float* wr = ws + WS_WP + icu * 16;
    #pragma unroll
    for (int m = 0; m < 15; m++) ho[m] = fmaf(a, wr[m], ho[m]);
  }

  // ---- decisions (gumbel-hard forward == first-argmax of logits+g)
  int bjH, bjD, bjY;
  {
    const float* gg = gH + (bl * 8 + k) * 5;
    float bv = ho[5] + gg[0]; int bj = 0;
    #pragma unroll
    for (int c = 1; c < 5; c++) {
      const float lv = ho[5 + c] + gg[c];
      if (lv > bv) { bv = lv; bj = c; }
    }
    bjH = bj;
  }
  {
    const float* gg = gd + (bl * 8 + k) * 5;
    float bv = ho[10] + gg[0]; int bj = 0;
    #pragma unroll
    for (int c = 1; c < 5; c++) {
      const float lv = ho[10 + c] + gg[c];
      if (lv > bv) { bv = lv; bj = c; }
    }
    bjD = bj;
  }
  {
    // mean over the 8 k-lanes of this slot, sequential order (matches np)
    const int gb = lane & 56;
    const float* gg = gy + bl * 5;
    float bv = 0.0f; int bj = 0;
    #pragma unroll
    for (int c = 0; c < 5; c++) {
      float acc = 0.0f;
      #pragma unroll
      for (int kk = 0; kk < 8; kk++) acc += __shfl(ho[c], gb + kk, 64);
      const float lv = acc * 0.125f + gg[c];
      if (c == 0 || lv > bv) { bv = lv; bj = c; }
    }
    bjY = bj;
  }

  // ---- qparams
  float hse, hqn, hqp, dse, dqn, dqp, yse, yqn, yqp;
  qparams(bjH, sH, 16777216.0, hse, hqn, hqp);
  qparams(bjD, sd,   262144.0, dse, dqn, dqp);
  qparams(bjY, sy,  2097152.0, yse, yqn, yqp);
  *(float4*)&qh[w][s][k][0] = make_float4(hse, hqn, hqp, 0.0f);

  // ---- b-links
  {
    const int oi = bl * 8 + k;
    const float by_ = 64.0f  * (float)bjY;   // 2*64*(4j)/8
    const float bH_ = 512.0f * (float)bjH;   // 2*64*(4j)
    const float bd_ = 8.0f   * (float)bjD;   // 2*(4j)
    out[OFF_BT + oi] = by_ + bH_ + bd_;
    out[OFF_BY + oi] = by_;
    out[OFF_BH + oi] = bH_;
    out[OFF_BD + oi] = bd_;
  }

  // ---- v_q (own site, 2 values)
  {
    float2 r;
    r.x = quantv(vr, dse, dqn, dqp);
    r.y = quantv(vi, dse, dqn, dqp);
    *(float2*)(out + OFF_V + bl * 16 + 2 * k) = r;
  }

  // ---- y_q: lane covers y[bl, k*16 .. k*16+15]
  #pragma unroll
  for (int c = 0; c < 4; c++) {
    const int fi = bl * 128 + k * 16 + 4 * c;
    const float4 xv = *(const float4*)(ym + fi);
    float4 r;
    r.x = quantv(xv.x, yse, yqn, yqp);
    r.y = quantv(xv.y, yse, yqn, yqp);
    r.z = quantv(xv.z, yse, yqn, yqp);
    r.w = quantv(xv.w, yse, yqn, yqp);
    *(float4*)(out + OFF_Y + fi) = r;
  }

  __syncthreads();   // publish qh across lanes

  // ---- H_q: per bl, 64 lanes stream 1024 consecutive floats (coalesced)
  const int k0 = (2 * lane) & 7;     // elem pair (k0, k0+1) for this lane
  #pragma unroll
  for (int b = 0; b < 8; b++) {
    const float4 qa = *(const float4*)&qh[w][b][k0][0];
    const float4 qb = *(const float4*)&qh[w][b][k0 + 1][0];
    const float* src = Hm + (blw + b) * 1024;
    float* dst = out + OFF_H + (blw + b) * 1024;
    #pragma unroll
    for (int c = 0; c < 4; c++) {
      const int fi = (c * 64 + lane) * 4;
      const float4 xh = *(const float4*)(src + fi);
      float4 r;
      r.x = quantv(xh.x, qa.x, qa.y, qa.z);
      r.y = quantv(xh.y, qa.x, qa.y, qa.z);
      r.z = quantv(xh.z, qb.x, qb.y, qb.z);
      r.w = quantv(xh.w, qb.x, qb.y, qb.z);
      *(float4*)(dst + fi) = r;
    }
  }
}

// ---------------------------------------------------------------- launch
extern "C" void kernel_launch(void* const* d_in, const int* in_sizes, int n_in,
                              void* d_out, int out_size, void* d_ws, size_t ws_size,
                              hipStream_t stream) {
  (void)in_sizes; (void)n_in; (void)out_size; (void)ws_size;
  const float* v   = (const float*)d_in[0];
  const float* Hm  = (const float*)d_in[1];
  const float* ym  = (const float*)d_in[2];
  const float* snr = (const float*)d_in[3];
  const float* gy  = (const float*)d_in[4];
  const float* gH  = (const float*)d_in[5];
  const float* gd  = (const float*)d_in[6];
  const float* W1  = (const float*)d_in[7];
  const float* B1  = (const float*)d_in[8];
  const float* W2  = (const float*)d_in[9];
  const float* B2  = (const float*)d_in[10];
  const float* W3  = (const float*)d_in[11];
  const float* B3  = (const float*)d_in[12];
  const float* Wy  = (const float*)d_in[13];
  const float* By  = (const float*)d_in[14];
  const float* Wh  = (const float*)d_in[15];
  const float* Bh  = (const float*)d_in[16];
  const float* Wd  = (const float*)d_in[17];
  const float* Bd  = (const float*)d_in[18];
  const float* sy  = (const float*)d_in[19];
  const float* sH  = (const float*)d_in[20];
  const float* sd  = (const float*)d_in[21];
  float* out = (float*)d_out;
  float* ws  = (float*)d_ws;

  k_power<<<NBL, 256, 0, stream>>>(Hm, ym, Wy, By, Wh, Bh, Wd, Bd, ws);
  k_avg<<<128, 256, 0, stream>>>(ws);
  k_main<<<512, 256, 0, stream>>>(v, Hm, ym, snr, gy, gH, gd,
                                  W1, B1, W2, B2, W3, B3,
                                  sy, sH, sd, ws, out);
}

// Round 4
// 74.458 us; speedup vs baseline: 2.4471x; 2.4471x over previous
//
#include <hip/hip_runtime.h>

// Problem constants: B=16, L=1024, K=8, N=64, Hh=64
#define NBL 16384

// workspace float offsets
#define WS_HPOW 0            // [NBL][8]
#define WS_YSUM 131072       // [NBL]
#define WS_AVG  147456       // [B][K]

// output float offsets
#define OFF_V  0
#define OFF_H  262144
#define OFF_Y  17039360
#define OFF_BT 19136512
#define OFF_BY 19267584
#define OFF_BH 19398656
#define OFF_BD 19529728

typedef short s8v __attribute__((ext_vector_type(8)));
typedef float f32x16 __attribute__((ext_vector_type(16)));
typedef unsigned int u32x4 __attribute__((ext_vector_type(4)));

#define WAVE_SYNC() asm volatile("s_waitcnt lgkmcnt(0)" ::: "memory")
#define MFMA(a, b, c) __builtin_amdgcn_mfma_f32_32x32x16_bf16(a, b, c, 0, 0, 0)

// ---------------------------------------------------------------- kernel A
__global__ __launch_bounds__(256) void k_power(const float* __restrict__ Hm,
                                               const float* __restrict__ ym,
                                               float* __restrict__ ws) {
  const int bl = blockIdx.x;
  const int t  = threadIdx.x;
  __shared__ float wsum[4][8];
  float4 h4 = *(const float4*)(Hm + bl * 1024 + t * 4);
  float s0 = h4.x * h4.x + h4.y * h4.y;
  float s1 = h4.z * h4.z + h4.w * h4.w;
  #pragma unroll
  for (int m = 4; m <= 32; m <<= 1) {
    s0 += __shfl_xor(s0, m, 64);
    s1 += __shfl_xor(s1, m, 64);
  }
  const int lane = t & 63, w = t >> 6;
  if (lane < 4) {
    wsum[w][2 * lane]     = s0;
    wsum[w][2 * lane + 1] = s1;
  }
  __syncthreads();
  if (t < 8)
    ws[WS_HPOW + bl * 8 + t] = wsum[0][t] + wsum[1][t] + wsum[2][t] + wsum[3][t];
  if (t >= 64 && t < 128) {
    const int u = t - 64;
    float p = 0.0f;
    if (u < 32) {
      float4 v4 = *(const float4*)(ym + bl * 128 + u * 4);
      p = v4.x * v4.x + v4.y * v4.y + v4.z * v4.z + v4.w * v4.w;
    }
    #pragma unroll
    for (int m = 1; m <= 32; m <<= 1) p += __shfl_xor(p, m, 64);
    if (u == 0) ws[WS_YSUM + bl] = p;
  }
}

// ---------------------------------------------------------------- kernel B
__global__ __launch_bounds__(256) void k_avg(float* __restrict__ ws) {
  const int bk = blockIdx.x;
  const int b = bk >> 3, k = bk & 7;
  const int t = threadIdx.x;
  __shared__ float red[256];
  float p = 0.0f;
  for (int l = t; l < 1024; l += 256)
    p += ws[WS_HPOW + ((b << 10) + l) * 8 + k];
  red[t] = p;
  __syncthreads();
  for (int st = 128; st > 0; st >>= 1) {
    if (t < st) red[t] += red[t + st];
    __syncthreads();
  }
  if (t == 0) ws[WS_AVG + bk] = red[0] * (1.0f / 1024.0f);
}

// ---------------------------------------------------------------- helpers
__device__ __forceinline__ unsigned packbf(float x, float y) {
  return (__float_as_uint(x) >> 16) | (__float_as_uint(y) & 0xFFFF0000u);
}

// truncation 4-split of 8 f32 values (e-order) into 4 bf16x8 fragments
__device__ __forceinline__ void build_frags(const float* v, s8v* F) {
  float s[4][8];
  #pragma unroll
  for (int e = 0; e < 8; e++) {
    const float x = v[e];
    const float a = __uint_as_float(__float_as_uint(x) & 0xFFFF0000u);
    const float r1 = x - a;
    const float b = __uint_as_float(__float_as_uint(r1) & 0xFFFF0000u);
    const float r2 = r1 - b;
    const float c = __uint_as_float(__float_as_uint(r2) & 0xFFFF0000u);
    const float d = r2 - c;
    s[0][e] = a; s[1][e] = b; s[2][e] = c; s[3][e] = d;
  }
  #pragma unroll
  for (int sp = 0; sp < 4; sp++) {
    u32x4 wv;
    wv.x = packbf(s[sp][0], s[sp][1]);
    wv.y = packbf(s[sp][2], s[sp][3]);
    wv.z = packbf(s[sp][4], s[sp][5]);
    wv.w = packbf(s[sp][6], s[sp][7]);
    F[sp] = __builtin_bit_cast(s8v, wv);
  }
}

// 10-product bf16x4 emulated-fp32 accumulate (terms down to 2^-32)
__device__ __forceinline__ f32x16 mac10(const s8v* A, const s8v* B, f32x16 c) {
  c = MFMA(A[0], B[0], c);
  c = MFMA(A[0], B[1], c); c = MFMA(A[1], B[0], c);
  c = MFMA(A[0], B[2], c); c = MFMA(A[1], B[1], c); c = MFMA(A[2], B[0], c);
  c = MFMA(A[0], B[3], c); c = MFMA(A[1], B[2], c); c = MFMA(A[2], B[1], c);
  c = MFMA(A[3], B[0], c);
  return c;
}

// A-fragment (weights W^T[j][ic]) from LDS: lane -> m=lane&31, k-octet by half
__device__ __forceinline__ void afrag(const float* Wt, int stride, int M, int t,
                                      int lane, s8v* F) {
  const int j = M * 32 + (lane & 31);
  const float* p = Wt + j * stride + t * 16 + 8 * (lane >> 5);
  float v[8];
  const float4 x0 = *(const float4*)p;
  const float4 x1 = *(const float4*)(p + 4);
  v[0] = x0.x; v[1] = x0.y; v[2] = x0.z; v[3] = x0.w;
  v[4] = x1.x; v[5] = x1.y; v[6] = x1.z; v[7] = x1.w;
  build_frags(v, F);
}

// C init from bias: reg r of mtile M holds j = 32M + 8(r>>2) + 4h + (r&3)
__device__ __forceinline__ f32x16 cinit(const float* bias, int M, int half) {
  f32x16 c;
  #pragma unroll
  for (int o = 0; o < 4; o++) {
    const float4 b4 = *(const float4*)(bias + M * 32 + o * 8 + 4 * half);
    c[4 * o + 0] = b4.x; c[4 * o + 1] = b4.y;
    c[4 * o + 2] = b4.z; c[4 * o + 3] = b4.w;
  }
  return c;
}

__device__ __forceinline__ f32x16 relu16(f32x16 a) {
  #pragma unroll
  for (int i = 0; i < 16; i++) a[i] = fmaxf(a[i], 0.0f);
  return a;
}

// B-fragment for kstep T built from previous layer's C registers.
// Receiver (half h) kstep T: k = 16T + 8h + e. Sources: regs r = 8(T&1)+4h+m
// of BOTH halves (own half supplies e-quad h, partner supplies e-quad 1-h).
template <int T>
__device__ __forceinline__ void bfragC(const f32x16& P0, const f32x16& P1,
                                       int half, s8v* F) {
  float v[8];
  #pragma unroll
  for (int m = 0; m < 4; m++) {
    float lo, hi;   // lo: serves receivers half0; hi: serves receivers half1
    if ((T >> 1) == 0) { lo = P0[8 * (T & 1) + m]; hi = P0[8 * (T & 1) + 4 + m]; }
    else               { lo = P1[8 * (T & 1) + m]; hi = P1[8 * (T & 1) + 4 + m]; }
    const float own  = half ? hi : lo;
    const float send = half ? lo : hi;
    const float recv = __shfl_xor(send, 32, 64);
    v[m]     = half ? recv : own;   // e = m   (from half-0 holder)
    v[4 + m] = half ? own : recv;   // e = 4+m (from half-1 holder)
  }
  build_frags(v, F);
}

// LSQ params for chosen branch j; j==0 encodes the zero branch
__device__ __forceinline__ void qparams(int j, const float* __restrict__ sv,
                                        double fsize, float& se, float& qn,
                                        float& qp) {
  se = 1.0f; qn = 0.0f; qp = 0.0f;
  if (j > 0) {
    const int p = 1 << (4 * j - 1);            // 8,128,2048,32768
    const float gscale = (float)(1.0 / sqrt(fsize * (double)(p - 1)));
    const float s  = sv[j - 1];
    const float sg = s * gscale;
    se = sg + (s - sg);                        // literal forward of s_eff
    qn = -(float)p; qp = (float)(p - 1);
  }
}

__device__ __forceinline__ float quantv(float x, float seff, float qn, float qp) {
  float xs = fminf(fmaxf(x / seff, qn), qp);   // exact IEEE div, matches np ref
  float r  = rintf(xs);                        // round half-even == jnp.round
  return (xs + (r - xs)) * seff;
}

// ---------------------------------------------------------------- kernel C
// wave = 32 sites (4 bl); MLP via 32x32x16 bf16 MFMA, fp32 emulated by 4-split
__global__ __launch_bounds__(512, 2) void k_main(
    const float* __restrict__ v,  const float* __restrict__ Hm,
    const float* __restrict__ ym, const float* __restrict__ snr,
    const float* __restrict__ gy, const float* __restrict__ gH,
    const float* __restrict__ gd,
    const float* __restrict__ W1, const float* __restrict__ B1,
    const float* __restrict__ W2, const float* __restrict__ B2,
    const float* __restrict__ W3, const float* __restrict__ B3,
    const float* __restrict__ Wy, const float* __restrict__ By,
    const float* __restrict__ Wh, const float* __restrict__ Bh,
    const float* __restrict__ Wd, const float* __restrict__ Bd,
    const float* __restrict__ sy, const float* __restrict__ sH,
    const float* __restrict__ sd,
    const float* __restrict__ ws, float* __restrict__ out) {

  __shared__ __align__(16) float sWt1[64 * 20];   // W1^T [j][16], cols 9..15 = 0
  __shared__ __align__(16) float sWt2[64 * 68];   // W2^T [j][ic]
  __shared__ __align__(16) float sWt3[64 * 68];   // W3^T [j][ic]
  __shared__ __align__(16) float sWtH[32 * 68];   // heads^T [m][ic], rows 15..31 = 0
  __shared__ __align__(16) float sB1v[64], sB2v[64], sB3v[64], sBHv[32];
  __shared__ __align__(16) float sFeat[8][16 * 33]; // per-wave featT / hoT
  __shared__ __align__(16) float sQHp[8][32 * 4];   // per-wave {se,qn,qp,0} per site
  __shared__ __align__(16) float sQYp[8][4 * 4];    // per-wave per-bl y params

  const int t = threadIdx.x;
  // ---- stage weights transposed (once per block)
  for (int i = t; i < 64 * 16; i += 512) {
    const int j = i >> 4, ic = i & 15;
    sWt1[j * 20 + ic] = (ic < 9) ? W1[ic * 64 + j] : 0.0f;
  }
  for (int i = t; i < 4096; i += 512) {
    const int j = i >> 6, ic = i & 63;
    sWt2[j * 68 + ic] = W2[ic * 64 + j];
    sWt3[j * 68 + ic] = W3[ic * 64 + j];
  }
  for (int i = t; i < 2048; i += 512) {
    const int m = i >> 6, ic = i & 63;
    float val = 0.0f;
    if (m < 5)       val = Wy[ic * 5 + m];
    else if (m < 10) val = Wh[ic * 5 + (m - 5)];
    else if (m < 15) val = Wd[ic * 5 + (m - 10)];
    sWtH[m * 68 + ic] = val;
  }
  if (t < 64) { sB1v[t] = B1[t]; sB2v[t] = B2[t]; sB3v[t] = B3[t]; }
  if (t < 32) sBHv[t] = (t < 5) ? By[t] : (t < 10) ? Bh[t - 5]
                       : (t < 15) ? Bd[t - 10] : 0.0f;
  __syncthreads();

  const int w    = t >> 6;
  const int lane = t & 63;
  const int half = lane >> 5;
  const int site = lane & 31;
  const int bl0  = (blockIdx.x * 8 + w) * 4;   // 4 bl per wave
  float* feat = &sFeat[w][0];                  // [16][33] featT, later hoT
  float* qhv  = &sQHp[w][0];
  float* qyv  = &sQYp[w][0];

  // ---- zero pad rows 9..15 of featT
  for (int i = lane; i < 7 * 33; i += 64) feat[9 * 33 + i] = 0.0f;

  // ---- features (lanes 0..31, one site each) into featT columns
  float vr = 0.0f, vi = 0.0f;
  if (lane < 32) {
    const int bl = bl0 + (site >> 3), k = site & 7;
    float tot = 0.0f, hp = 0.0f;
    #pragma unroll
    for (int kk = 0; kk < 8; kk++) {
      const float hv = ws[WS_HPOW + bl * 8 + kk];
      tot += hv;
      if (kk == k) hp = hv;
    }
    vr = v[bl * 16 + 2 * k]; vi = v[bl * 16 + 2 * k + 1];
    feat[0 * 33 + site] = vr;
    feat[1 * 33 + site] = vi;
    feat[2 * 33 + site] = snr[bl * 8 + k];
    feat[3 * 33 + site] = hp;
    feat[4 * 33 + site] = ws[WS_AVG + (bl >> 10) * 8 + k];
    feat[5 * 33 + site] = log1pf(hp / (tot - hp + 1e-10f));
    feat[6 * 33 + site] = log1pf(tot);
    feat[7 * 33 + site] = log1pf(ws[WS_YSUM + bl]);
    feat[8 * 33 + site] = sqrtf(vr * vr + vi * vi + 1e-10f);
  }
  WAVE_SYNC();

  s8v Af[4], Bf[4];

  // ---- layer 1 (K=16: features 0..8 + zero pad)
  {
    float fv[8];
    #pragma unroll
    for (int e = 0; e < 8; e++) fv[e] = feat[(8 * half + e) * 33 + site];
    build_frags(fv, Bf);
  }
  f32x16 c0 = cinit(sB1v, 0, half), c1 = cinit(sB1v, 1, half);
  afrag(sWt1, 20, 0, 0, lane, Af); c0 = mac10(Af, Bf, c0);
  afrag(sWt1, 20, 1, 0, lane, Af); c1 = mac10(Af, Bf, c1);
  c0 = relu16(c0); c1 = relu16(c1);

  // ---- layer 2 (K=64, 4 ksteps)
  {
    f32x16 n0 = cinit(sB2v, 0, half), n1 = cinit(sB2v, 1, half);
    bfragC<0>(c0, c1, half, Bf);
    afrag(sWt2, 68, 0, 0, lane, Af); n0 = mac10(Af, Bf, n0);
    afrag(sWt2, 68, 1, 0, lane, Af); n1 = mac10(Af, Bf, n1);
    bfragC<1>(c0, c1, half, Bf);
    afrag(sWt2, 68, 0, 1, lane, Af); n0 = mac10(Af, Bf, n0);
    afrag(sWt2, 68, 1, 1, lane, Af); n1 = mac10(Af, Bf, n1);
    bfragC<2>(c0, c1, half, Bf);
    afrag(sWt2, 68, 0, 2, lane, Af); n0 = mac10(Af, Bf, n0);
    afrag(sWt2, 68, 1, 2, lane, Af); n1 = mac10(Af, Bf, n1);
    bfragC<3>(c0, c1, half, Bf);
    afrag(sWt2, 68, 0, 3, lane, Af); n0 = mac10(Af, Bf, n0);
    afrag(sWt2, 68, 1, 3, lane, Af); n1 = mac10(Af, Bf, n1);
    c0 = relu16(n0); c1 = relu16(n1);
  }
  // ---- layer 3
  {
    f32x16 n0 = cinit(sB3v, 0, half), n1 = cinit(sB3v, 1, half);
    bfragC<0>(c0, c1, half, Bf);
    afrag(sWt3, 68, 0, 0, lane, Af); n0 = mac10(Af, Bf, n0);
    afrag(sWt3, 68, 1, 0, lane, Af); n1 = mac10(Af, Bf, n1);
    bfragC<1>(c0, c1, half, Bf);
    afrag(sWt3, 68, 0, 1, lane, Af); n0 = mac10(Af, Bf, n0);
    afrag(sWt3, 68, 1, 1, lane, Af); n1 = mac10(Af, Bf, n1);
    bfragC<2>(c0, c1, half, Bf);
    afrag(sWt3, 68, 0, 2, lane, Af); n0 = mac10(Af, Bf, n0);
    afrag(sWt3, 68, 1, 2, lane, Af); n1 = mac10(Af, Bf, n1);
    bfragC<3>(c0, c1, half, Bf);
    afrag(sWt3, 68, 0, 3, lane, Af); n0 = mac10(Af, Bf, n0);
    afrag(sWt3, 68, 1, 3, lane, Af); n1 = mac10(Af, Bf, n1);
    c0 = relu16(n0); c1 = relu16(n1);
  }
  // ---- heads (M=32: 15 real logits, rest zero-weight)
  {
    f32x16 hc = cinit(sBHv, 0, half);
    bfragC<0>(c0, c1, half, Bf);
    afrag(sWtH, 68, 0, 0, lane, Af); hc = mac10(Af, Bf, hc);
    bfragC<1>(c0, c1, half, Bf);
    afrag(sWtH, 68, 0, 1, lane, Af); hc = mac10(Af, Bf, hc);
    bfragC<2>(c0, c1, half, Bf);
    afrag(sWtH, 68, 0, 2, lane, Af); hc = mac10(Af, Bf, hc);
    bfragC<3>(c0, c1, half, Bf);
    afrag(sWtH, 68, 0, 3, lane, Af); hc = mac10(Af, Bf, hc);
    // scatter logits to hoT (reuses featT; features are dead)
    #pragma unroll
    for (int r = 0; r < 8; r++) {
      const int j = 8 * (r >> 2) + 4 * half + (r & 3);   // 0..15
      feat[j * 33 + site] = hc[r];
    }
  }
  WAVE_SYNC();

  // ---- decisions + qparams + b-links + v_q (lanes 0..31; exact R3 math)
  if (lane < 32) {
    const int bl = bl0 + (site >> 3);
    float ho[15];
    #pragma unroll
    for (int m = 0; m < 15; m++) ho[m] = feat[m * 33 + site];
    int bjH, bjD, bjY;
    {
      const float* gg = gH + (bl0 * 8 + site) * 5;
      float bv = ho[5] + gg[0]; int bj = 0;
      #pragma unroll
      for (int c = 1; c < 5; c++) {
        const float lv = ho[5 + c] + gg[c];
        if (lv > bv) { bv = lv; bj = c; }
      }
      bjH = bj;
    }
    {
      const float* gg = gd + (bl0 * 8 + site) * 5;
      float bv = ho[10] + gg[0]; int bj = 0;
      #pragma unroll
      for (int c = 1; c < 5; c++) {
        const float lv = ho[10 + c] + gg[c];
        if (lv > bv) { bv = lv; bj = c; }
      }
      bjD = bj;
    }
    {
      const int bs = site & 24;           // blo*8
      const float* gg = gy + bl * 5;
      float bv = 0.0f; int bj = 0;
      #pragma unroll
      for (int c = 0; c < 5; c++) {
        float acc = 0.0f;
        #pragma unroll
        for (int kk = 0; kk < 8; kk++) acc += feat[c * 33 + bs + kk];
        const float lv = acc * 0.125f + gg[c];
        if (c == 0 || lv > bv) { bv = lv; bj = c; }
      }
      bjY = bj;
    }
    float hse, hqn, hqp, dse, dqn, dqp, yse, yqn, yqp;
    qparams(bjH, sH, 16777216.0, hse, hqn, hqp);
    qparams(bjD, sd,   262144.0, dse, dqn, dqp);
    qparams(bjY, sy,  2097152.0, yse, yqn, yqp);
    *(float4*)(qhv + site * 4) = make_float4(hse, hqn, hqp, 0.0f);
    if ((site & 7) == 0)
      *(float4*)(qyv + (site >> 3) * 4) = make_float4(yse, yqn, yqp, 0.0f);
    {
      const int oi = bl0 * 8 + site;
      const float by_ = 64.0f  * (float)bjY;
      const float bH_ = 512.0f * (float)bjH;
      const float bd_ = 8.0f   * (float)bjD;
      out[OFF_BT + oi] = by_ + bH_ + bd_;
      out[OFF_BY + oi] = by_;
      out[OFF_BH + oi] = bH_;
      out[OFF_BD + oi] = bd_;
    }
    {
      float2 r;
      r.x = quantv(vr, dse, dqn, dqp);
      r.y = quantv(vi, dse, dqn, dqp);
      *(float2*)(out + OFF_V + bl0 * 16 + site * 2) = r;
    }
  }
  WAVE_SYNC();

  // ---- y_q: 4 bl x 128 floats, all lanes
  #pragma unroll
  for (int c = 0; c < 2; c++) {
    const int fi = c * 64 + lane;        // float4 index in wave's 512 floats
    const int brel = fi >> 5, i = fi & 31;
    const float4 qy4 = *(const float4*)(qyv + brel * 4);
    const int gi = (bl0 + brel) * 128 + i * 4;
    const float4 xv = *(const float4*)(ym + gi);
    float4 r;
    r.x = quantv(xv.x, qy4.x, qy4.y, qy4.z);
    r.y = quantv(xv.y, qy4.x, qy4.y, qy4.z);
    r.z = quantv(xv.z, qy4.x, qy4.y, qy4.z);
    r.w = quantv(xv.w, qy4.x, qy4.y, qy4.z);
    *(float4*)(out + OFF_Y + gi) = r;
  }

  // ---- H_q: per bl, 64 lanes stream 1024 floats (coalesced; R3 pattern)
  const int k0 = (2 * lane) & 7;
  #pragma unroll
  for (int b = 0; b < 4; b++) {
    const float4 qa = *(const float4*)(qhv + ((b << 3) + k0) * 4);
    const float4 qb = *(const float4*)(qhv + ((b << 3) + k0 + 1) * 4);
    const float* src = Hm + (bl0 + b) * 1024;
    float* dst = out + OFF_H + (bl0 + b) * 1024;
    #pragma unroll
    for (int c = 0; c < 4; c++) {
      const int fi = (c * 64 + lane) * 4;
      const float4 xh = *(const float4*)(src + fi);
      float4 r;
      r.x = quantv(xh.x, qa.x, qa.y, qa.z);
      r.y = quantv(xh.y, qa.x, qa.y, qa.z);
      r.z = quantv(xh.z, qb.x, qb.y, qb.z);
      r.w = quantv(xh.w, qb.x, qb.y, qb.z);
      *(float4*)(dst + fi) = r;
    }
  }
}

// ---------------------------------------------------------------- launch
extern "C" void kernel_launch(void* const* d_in, const int* in_sizes, int n_in,
                              void* d_out, int out_size, void* d_ws, size_t ws_size,
                              hipStream_t stream) {
  (void)in_sizes; (void)n_in; (void)out_size; (void)ws_size;
  const float* v   = (const float*)d_in[0];
  const float* Hm  = (const float*)d_in[1];
  const float* ym  = (const float*)d_in[2];
  const float* snr = (const float*)d_in[3];
  const float* gy  = (const float*)d_in[4];
  const float* gH  = (const float*)d_in[5];
  const float* gd  = (const float*)d_in[6];
  const float* W1  = (const float*)d_in[7];
  const float* B1  = (const float*)d_in[8];
  const float* W2  = (const float*)d_in[9];
  const float* B2  = (const float*)d_in[10];
  const float* W3  = (const float*)d_in[11];
  const float* B3  = (const float*)d_in[12];
  const float* Wy  = (const float*)d_in[13];
  const float* By  = (const float*)d_in[14];
  const float* Wh  = (const float*)d_in[15];
  const float* Bh  = (const float*)d_in[16];
  const float* Wd  = (const float*)d_in[17];
  const float* Bd  = (const float*)d_in[18];
  const float* sy  = (const float*)d_in[19];
  const float* sH  = (const float*)d_in[20];
  const float* sd  = (const float*)d_in[21];
  float* out = (float*)d_out;
  float* ws  = (float*)d_ws;

  k_power<<<NBL, 256, 0, stream>>>(Hm, ym, ws);
  k_avg<<<128, 256, 0, stream>>>(ws);
  k_main<<<512, 512, 0, stream>>>(v, Hm, ym, snr, gy, gH, gd,
                                  W1, B1, W2, B2, W3, B3,
                                  Wy, By, Wh, Bh, Wd, Bd,
                                  sy, sH, sd, ws, out);
}

// Round 5
// 71.791 us; speedup vs baseline: 2.5380x; 1.0371x over previous
//
#include <hip/hip_runtime.h>

// Problem constants: B=16, L=1024, K=8, N=64, Hh=64
#define NBL 16384

// workspace float offsets
#define WS_HPOW 0            // [NBL][8]
#define WS_YSUM 131072       // [NBL]
#define WS_AVG  147456       // [B][K]

// output float offsets
#define OFF_V  0
#define OFF_H  262144
#define OFF_Y  17039360
#define OFF_BT 19136512
#define OFF_BY 19267584
#define OFF_BH 19398656
#define OFF_BD 19529728

typedef short s8v __attribute__((ext_vector_type(8)));
typedef float f32x16 __attribute__((ext_vector_type(16)));
typedef unsigned int u32x4 __attribute__((ext_vector_type(4)));

#define WAVE_SYNC() asm volatile("s_waitcnt lgkmcnt(0)" ::: "memory")
#define MFMA(a, b, c) __builtin_amdgcn_mfma_f32_32x32x16_bf16(a, b, c, 0, 0, 0)
#define NCALL 22   // 2 (L1) + 8 (L2) + 8 (L3) + 4 (heads)

// ---------------------------------------------------------------- kernel A
__global__ __launch_bounds__(256) void k_power(const float* __restrict__ Hm,
                                               const float* __restrict__ ym,
                                               float* __restrict__ ws) {
  const int bl = blockIdx.x;
  const int t  = threadIdx.x;
  __shared__ float wsum[4][8];
  float4 h4 = *(const float4*)(Hm + bl * 1024 + t * 4);
  float s0 = h4.x * h4.x + h4.y * h4.y;
  float s1 = h4.z * h4.z + h4.w * h4.w;
  #pragma unroll
  for (int m = 4; m <= 32; m <<= 1) {
    s0 += __shfl_xor(s0, m, 64);
    s1 += __shfl_xor(s1, m, 64);
  }
  const int lane = t & 63, w = t >> 6;
  if (lane < 4) {
    wsum[w][2 * lane]     = s0;
    wsum[w][2 * lane + 1] = s1;
  }
  __syncthreads();
  if (t < 8)
    ws[WS_HPOW + bl * 8 + t] = wsum[0][t] + wsum[1][t] + wsum[2][t] + wsum[3][t];
  if (t >= 64 && t < 128) {
    const int u = t - 64;
    float p = 0.0f;
    if (u < 32) {
      float4 v4 = *(const float4*)(ym + bl * 128 + u * 4);
      p = v4.x * v4.x + v4.y * v4.y + v4.z * v4.z + v4.w * v4.w;
    }
    #pragma unroll
    for (int m = 1; m <= 32; m <<= 1) p += __shfl_xor(p, m, 64);
    if (u == 0) ws[WS_YSUM + bl] = p;
  }
}

// ---------------------------------------------------------------- kernel B
__global__ __launch_bounds__(256) void k_avg(float* __restrict__ ws) {
  const int bk = blockIdx.x;
  const int b = bk >> 3, k = bk & 7;
  const int t = threadIdx.x;
  __shared__ float red[256];
  float p = 0.0f;
  for (int l = t; l < 1024; l += 256)
    p += ws[WS_HPOW + ((b << 10) + l) * 8 + k];
  red[t] = p;
  __syncthreads();
  for (int st = 128; st > 0; st >>= 1) {
    if (t < st) red[t] += red[t + st];
    __syncthreads();
  }
  if (t == 0) ws[WS_AVG + bk] = red[0] * (1.0f / 1024.0f);
}

// ---------------------------------------------------------------- helpers
__device__ __forceinline__ unsigned packbf(float x, float y) {
  return (__float_as_uint(x) >> 16) | (__float_as_uint(y) & 0xFFFF0000u);
}

// exact 3-term truncation split of fp32 (4th term is identically zero)
__device__ __forceinline__ void split3(float x, float& a, float& b, float& c) {
  a = __uint_as_float(__float_as_uint(x) & 0xFFFF0000u);
  const float r1 = x - a;
  b = __uint_as_float(__float_as_uint(r1) & 0xFFFF0000u);
  c = r1 - b;        // <= 8 significand bits: exactly a bf16-maskable value
}

__device__ __forceinline__ void build_frags3(const float* v, s8v* F) {
  float s0[8], s1[8], s2[8];
  #pragma unroll
  for (int e = 0; e < 8; e++) split3(v[e], s0[e], s1[e], s2[e]);
  u32x4 w0, w1, w2;
  w0.x = packbf(s0[0], s0[1]); w0.y = packbf(s0[2], s0[3]);
  w0.z = packbf(s0[4], s0[5]); w0.w = packbf(s0[6], s0[7]);
  w1.x = packbf(s1[0], s1[1]); w1.y = packbf(s1[2], s1[3]);
  w1.z = packbf(s1[4], s1[5]); w1.w = packbf(s1[6], s1[7]);
  w2.x = packbf(s2[0], s2[1]); w2.y = packbf(s2[2], s2[3]);
  w2.z = packbf(s2[4], s2[5]); w2.w = packbf(s2[6], s2[7]);
  F[0] = __builtin_bit_cast(s8v, w0);
  F[1] = __builtin_bit_cast(s8v, w1);
  F[2] = __builtin_bit_cast(s8v, w2);
}

// 8-product emulated-fp32 MAC: identical products/order as R4's mac10 with
// the two always-zero (split-3) products removed -> bit-identical result
__device__ __forceinline__ f32x16 mac8(const s8v* A, const s8v* B, f32x16 c) {
  c = MFMA(A[0], B[0], c);
  c = MFMA(A[0], B[1], c); c = MFMA(A[1], B[0], c);
  c = MFMA(A[0], B[2], c); c = MFMA(A[1], B[1], c); c = MFMA(A[2], B[0], c);
  c = MFMA(A[1], B[2], c); c = MFMA(A[2], B[1], c);
  return c;
}

// pre-split A-fragment load: 3 conflict-free ds_read_b128, zero VALU
__device__ __forceinline__ void frag_ld(const u32x4* __restrict__ sFr, int call,
                                        int lane, s8v* F) {
  F[0] = __builtin_bit_cast(s8v, sFr[(call * 3 + 0) * 64 + lane]);
  F[1] = __builtin_bit_cast(s8v, sFr[(call * 3 + 1) * 64 + lane]);
  F[2] = __builtin_bit_cast(s8v, sFr[(call * 3 + 2) * 64 + lane]);
}

// weight element for staging: A[j=32M+(lane&31)][ic=16T+8*(lane>>5)+e]
__device__ __forceinline__ float w_elem(int call, int lane, int e,
                                        const float* __restrict__ W1,
                                        const float* __restrict__ W2,
                                        const float* __restrict__ W3,
                                        const float* __restrict__ Wy,
                                        const float* __restrict__ Wh,
                                        const float* __restrict__ Wd) {
  const int h = lane >> 5, m = lane & 31;
  if (call < 2) {                      // L1: M=call, T=0, K padded 9->16
    const int ic = 8 * h + e;
    return (ic < 9) ? W1[ic * 64 + call * 32 + m] : 0.0f;
  } else if (call < 10) {              // L2: call = 2 + T*2 + M
    const int idx = call - 2, T = idx >> 1, M = idx & 1;
    return W2[(16 * T + 8 * h + e) * 64 + 32 * M + m];
  } else if (call < 18) {              // L3
    const int idx = call - 10, T = idx >> 1, M = idx & 1;
    return W3[(16 * T + 8 * h + e) * 64 + 32 * M + m];
  } else {                             // heads: call = 18 + T, rows 15..31 = 0
    const int ic = 16 * (call - 18) + 8 * h + e;
    if (m < 5)  return Wy[ic * 5 + m];
    if (m < 10) return Wh[ic * 5 + m - 5];
    if (m < 15) return Wd[ic * 5 + m - 10];
    return 0.0f;
  }
}

// C init from bias: reg r of mtile M holds j = 32M + 8(r>>2) + 4h + (r&3)
__device__ __forceinline__ f32x16 cinit(const float* bias, int M, int half) {
  f32x16 c;
  #pragma unroll
  for (int o = 0; o < 4; o++) {
    const float4 b4 = *(const float4*)(bias + M * 32 + o * 8 + 4 * half);
    c[4 * o + 0] = b4.x; c[4 * o + 1] = b4.y;
    c[4 * o + 2] = b4.z; c[4 * o + 3] = b4.w;
  }
  return c;
}

__device__ __forceinline__ f32x16 relu16(f32x16 a) {
  #pragma unroll
  for (int i = 0; i < 16; i++) a[i] = fmaxf(a[i], 0.0f);
  return a;
}

// B-fragment for kstep T from previous layer's C registers (validated in R4)
template <int T>
__device__ __forceinline__ void bfragC3(const f32x16& P0, const f32x16& P1,
                                        int half, s8v* F) {
  float v[8];
  #pragma unroll
  for (int m = 0; m < 4; m++) {
    float lo, hi;
    if ((T >> 1) == 0) { lo = P0[8 * (T & 1) + m]; hi = P0[8 * (T & 1) + 4 + m]; }
    else               { lo = P1[8 * (T & 1) + m]; hi = P1[8 * (T & 1) + 4 + m]; }
    const float own  = half ? hi : lo;
    const float send = half ? lo : hi;
    const float recv = __shfl_xor(send, 32, 64);
    v[m]     = half ? recv : own;
    v[4 + m] = half ? own : recv;
  }
  build_frags3(v, F);
}

// LSQ params for chosen branch j; j==0 encodes the zero branch
__device__ __forceinline__ void qparams(int j, const float* __restrict__ sv,
                                        double fsize, float& se, float& qn,
                                        float& qp) {
  se = 1.0f; qn = 0.0f; qp = 0.0f;
  if (j > 0) {
    const int p = 1 << (4 * j - 1);            // 8,128,2048,32768
    const float gscale = (float)(1.0 / sqrt(fsize * (double)(p - 1)));
    const float s  = sv[j - 1];
    const float sg = s * gscale;
    se = sg + (s - sg);                        // literal forward of s_eff
    qn = -(float)p; qp = (float)(p - 1);
  }
}

__device__ __forceinline__ float quantv(float x, float seff, float qn, float qp) {
  float xs = fminf(fmaxf(x / seff, qn), qp);   // exact IEEE div, matches np ref
  float r  = rintf(xs);                        // round half-even == jnp.round
  return (xs + (r - xs)) * seff;
}

// ---------------------------------------------------------------- kernel C
// wave = 32 sites (4 bl); weights pre-split to bf16 frags in LDS once/block
__global__ __launch_bounds__(512, 4) void k_main(
    const float* __restrict__ v,  const float* __restrict__ Hm,
    const float* __restrict__ ym, const float* __restrict__ snr,
    const float* __restrict__ gy, const float* __restrict__ gH,
    const float* __restrict__ gd,
    const float* __restrict__ W1, const float* __restrict__ B1,
    const float* __restrict__ W2, const float* __restrict__ B2,
    const float* __restrict__ W3, const float* __restrict__ B3,
    const float* __restrict__ Wy, const float* __restrict__ By,
    const float* __restrict__ Wh, const float* __restrict__ Bh,
    const float* __restrict__ Wd, const float* __restrict__ Bd,
    const float* __restrict__ sy, const float* __restrict__ sH,
    const float* __restrict__ sd,
    const float* __restrict__ ws, float* __restrict__ out) {

  __shared__ u32x4 sFr[NCALL * 3 * 64];          // 67584 B pre-split A-frags
  __shared__ float sB1v[64], sB2v[64], sB3v[64], sBHv[32];
  __shared__ __align__(16) float sQHp[8][32 * 4]; // per-wave H qparams/site
  __shared__ __align__(16) float sQYp[8][16];     // per-wave y qparams/bl

  const int t = threadIdx.x;
  // ---- stage pre-split weight fragments (once per block)
  for (int i = t; i < NCALL * 768; i += 512) {
    const int call = i / 768;
    const int rem  = i - call * 768;
    const int sp   = rem >> 8;            // split 0..2
    const int ln   = (rem >> 2) & 63;
    const int wd   = rem & 3;
    const float x0 = w_elem(call, ln, 2 * wd,     W1, W2, W3, Wy, Wh, Wd);
    const float x1 = w_elem(call, ln, 2 * wd + 1, W1, W2, W3, Wy, Wh, Wd);
    float a0, b0, c0, a1, b1, c1;
    split3(x0, a0, b0, c0);
    split3(x1, a1, b1, c1);
    const float lo = (sp == 0) ? a0 : (sp == 1) ? b0 : c0;
    const float hi = (sp == 0) ? a1 : (sp == 1) ? b1 : c1;
    ((unsigned*)sFr)[i] = packbf(lo, hi);
  }
  if (t < 64) { sB1v[t] = B1[t]; sB2v[t] = B2[t]; sB3v[t] = B3[t]; }
  if (t < 32) sBHv[t] = (t < 5) ? By[t] : (t < 10) ? Bh[t - 5]
                       : (t < 15) ? Bd[t - 10] : 0.0f;
  __syncthreads();

  const int w    = t >> 6;
  const int lane = t & 63;
  const int half = lane >> 5;
  const int site = lane & 31;
  const int bl0  = (blockIdx.x * 8 + w) * 4;   // 4 bl per wave
  const int bl   = bl0 + (site >> 3);
  const int k    = site & 7;
  float* qhv = &sQHp[w][0];
  float* qyv = &sQYp[w][0];

  // ---- features (registers only; half0: f0..f7, half1: f8 + zero pad)
  const float vr = v[bl * 16 + 2 * k], vi = v[bl * 16 + 2 * k + 1];
  s8v Af[3], Bf[3];
  {
    float fv[8];
    if (half == 0) {
      float tot = 0.0f, hp = 0.0f;
      #pragma unroll
      for (int kk = 0; kk < 8; kk++) {
        const float hv = ws[WS_HPOW + bl * 8 + kk];
        tot += hv;
        if (kk == k) hp = hv;
      }
      fv[0] = vr;
      fv[1] = vi;
      fv[2] = snr[bl * 8 + k];
      fv[3] = hp;
      fv[4] = ws[WS_AVG + (bl >> 10) * 8 + k];
      fv[5] = log1pf(hp / (tot - hp + 1e-10f));
      fv[6] = log1pf(tot);
      fv[7] = log1pf(ws[WS_YSUM + bl]);
    } else {
      fv[0] = sqrtf(vr * vr + vi * vi + 1e-10f);
      #pragma unroll
      for (int e = 1; e < 8; e++) fv[e] = 0.0f;
    }
    build_frags3(fv, Bf);
  }

  // ---- layer 1 (K=16)
  f32x16 c0 = cinit(sB1v, 0, half), c1 = cinit(sB1v, 1, half);
  frag_ld(sFr, 0, lane, Af); c0 = mac8(Af, Bf, c0);
  frag_ld(sFr, 1, lane, Af); c1 = mac8(Af, Bf, c1);
  c0 = relu16(c0); c1 = relu16(c1);

  // ---- layer 2 (K=64, 4 ksteps)
  {
    f32x16 n0 = cinit(sB2v, 0, half), n1 = cinit(sB2v, 1, half);
    bfragC3<0>(c0, c1, half, Bf);
    frag_ld(sFr, 2, lane, Af); n0 = mac8(Af, Bf, n0);
    frag_ld(sFr, 3, lane, Af); n1 = mac8(Af, Bf, n1);
    bfragC3<1>(c0, c1, half, Bf);
    frag_ld(sFr, 4, lane, Af); n0 = mac8(Af, Bf, n0);
    frag_ld(sFr, 5, lane, Af); n1 = mac8(Af, Bf, n1);
    bfragC3<2>(c0, c1, half, Bf);
    frag_ld(sFr, 6, lane, Af); n0 = mac8(Af, Bf, n0);
    frag_ld(sFr, 7, lane, Af); n1 = mac8(Af, Bf, n1);
    bfragC3<3>(c0, c1, half, Bf);
    frag_ld(sFr, 8, lane, Af); n0 = mac8(Af, Bf, n0);
    frag_ld(sFr, 9, lane, Af); n1 = mac8(Af, Bf, n1);
    c0 = relu16(n0); c1 = relu16(n1);
  }
  // ---- layer 3
  {
    f32x16 n0 = cinit(sB3v, 0, half), n1 = cinit(sB3v, 1, half);
    bfragC3<0>(c0, c1, half, Bf);
    frag_ld(sFr, 10, lane, Af); n0 = mac8(Af, Bf, n0);
    frag_ld(sFr, 11, lane, Af); n1 = mac8(Af, Bf, n1);
    bfragC3<1>(c0, c1, half, Bf);
    frag_ld(sFr, 12, lane, Af); n0 = mac8(Af, Bf, n0);
    frag_ld(sFr, 13, lane, Af); n1 = mac8(Af, Bf, n1);
    bfragC3<2>(c0, c1, half, Bf);
    frag_ld(sFr, 14, lane, Af); n0 = mac8(Af, Bf, n0);
    frag_ld(sFr, 15, lane, Af); n1 = mac8(Af, Bf, n1);
    bfragC3<3>(c0, c1, half, Bf);
    frag_ld(sFr, 16, lane, Af); n0 = mac8(Af, Bf, n0);
    frag_ld(sFr, 17, lane, Af); n1 = mac8(Af, Bf, n1);
    c0 = relu16(n0); c1 = relu16(n1);
  }
  // ---- heads (M-tile 0 only; rows 15..31 zero)
  f32x16 hc = cinit(sBHv, 0, half);
  {
    bfragC3<0>(c0, c1, half, Bf);
    frag_ld(sFr, 18, lane, Af); hc = mac8(Af, Bf, hc);
    bfragC3<1>(c0, c1, half, Bf);
    frag_ld(sFr, 19, lane, Af); hc = mac8(Af, Bf, hc);
    bfragC3<2>(c0, c1, half, Bf);
    frag_ld(sFr, 20, lane, Af); hc = mac8(Af, Bf, hc);
    bfragC3<3>(c0, c1, half, Bf);
    frag_ld(sFr, 21, lane, Af); hc = mac8(Af, Bf, hc);
  }

  // ---- gather all 16 logits of this lane's site into registers
  float ho[16];
  {
    float hop[8];
    #pragma unroll
    for (int r = 0; r < 8; r++) hop[r] = __shfl_xor(hc[r], 32, 64);
    if (half == 0) {
      #pragma unroll
      for (int r = 0; r < 8; r++) {
        ho[8 * (r >> 2) + (r & 3)]     = hc[r];
        ho[8 * (r >> 2) + 4 + (r & 3)] = hop[r];
      }
    } else {
      #pragma unroll
      for (int r = 0; r < 8; r++) {
        ho[8 * (r >> 2) + 4 + (r & 3)] = hc[r];
        ho[8 * (r >> 2) + (r & 3)]     = hop[r];
      }
    }
  }

  // ---- decisions (all lanes, both halves redundant; exact R4 math)
  int bjH, bjD, bjY;
  {
    const float* gg = gH + (bl0 * 8 + site) * 5;
    float bv = ho[5] + gg[0]; int bj = 0;
    #pragma unroll
    for (int c = 1; c < 5; c++) {
      const float lv = ho[5 + c] + gg[c];
      if (lv > bv) { bv = lv; bj = c; }
    }
    bjH = bj;
  }
  {
    const float* gg = gd + (bl0 * 8 + site) * 5;
    float bv = ho[10] + gg[0]; int bj = 0;
    #pragma unroll
    for (int c = 1; c < 5; c++) {
      const float lv = ho[10 + c] + gg[c];
      if (lv > bv) { bv = lv; bj = c; }
    }
    bjD = bj;
  }
  {
    const int gb = lane & 24;         // site-group base (half0 source lanes)
    const float* gg = gy + bl * 5;
    float bv = 0.0f; int bj = 0;
    #pragma unroll
    for (int c = 0; c < 5; c++) {
      float acc = 0.0f;
      #pragma unroll
      for (int kk = 0; kk < 8; kk++) acc += __shfl(ho[c], gb + kk, 64);
      const float lv = acc * 0.125f + gg[c];
      if (c == 0 || lv > bv) { bv = lv; bj = c; }
    }
    bjY = bj;
  }

  float hse, hqn, hqp, dse, dqn, dqp, yse, yqn, yqp;
  qparams(bjH, sH, 16777216.0, hse, hqn, hqp);
  qparams(bjD, sd,   262144.0, dse, dqn, dqp);
  qparams(bjY, sy,  2097152.0, yse, yqn, yqp);

  if (lane < 32) {
    *(float4*)(qhv + site * 4) = make_float4(hse, hqn, hqp, 0.0f);
    if ((site & 7) == 0)
      *(float4*)(qyv + (site >> 3) * 4) = make_float4(yse, yqn, yqp, 0.0f);
    {   // b-links
      const int oi = bl0 * 8 + site;
      const float by_ = 64.0f  * (float)bjY;
      const float bH_ = 512.0f * (float)bjH;
      const float bd_ = 8.0f   * (float)bjD;
      out[OFF_BT + oi] = by_ + bH_ + bd_;
      out[OFF_BY + oi] = by_;
      out[OFF_BH + oi] = bH_;
      out[OFF_BD + oi] = bd_;
    }
    {   // v_q
      float2 r;
      r.x = quantv(vr, dse, dqn, dqp);
      r.y = quantv(vi, dse, dqn, dqp);
      *(float2*)(out + OFF_V + bl0 * 16 + site * 2) = r;
    }
  }
  WAVE_SYNC();   // publish qh/qy across lanes

  // ---- y_q: 4 bl x 128 floats, all lanes
  #pragma unroll
  for (int c = 0; c < 2; c++) {
    const int fi = c * 64 + lane;
    const int brel = fi >> 5, i = fi & 31;
    const float4 qy4 = *(const float4*)(qyv + brel * 4);
    const int gi = (bl0 + brel) * 128 + i * 4;
    const float4 xv = *(const float4*)(ym + gi);
    float4 r;
    r.x = quantv(xv.x, qy4.x, qy4.y, qy4.z);
    r.y = quantv(xv.y, qy4.x, qy4.y, qy4.z);
    r.z = quantv(xv.z, qy4.x, qy4.y, qy4.z);
    r.w = quantv(xv.w, qy4.x, qy4.y, qy4.z);
    *(float4*)(out + OFF_Y + gi) = r;
  }

  // ---- H_q: per bl, 64 lanes stream 1024 floats (coalesced)
  const int k0 = (2 * lane) & 7;
  #pragma unroll
  for (int b = 0; b < 4; b++) {
    const float4 qa = *(const float4*)(qhv + ((b << 3) + k0) * 4);
    const float4 qb = *(const float4*)(qhv + ((b << 3) + k0 + 1) * 4);
    const float* src = Hm + (bl0 + b) * 1024;
    float* dst = out + OFF_H + (bl0 + b) * 1024;
    #pragma unroll
    for (int c = 0; c < 4; c++) {
      const int fi = (c * 64 + lane) * 4;
      const float4 xh = *(const float4*)(src + fi);
      float4 r;
      r.x = quantv(xh.x, qa.x, qa.y, qa.z);
      r.y = quantv(xh.y, qa.x, qa.y, qa.z);
      r.z = quantv(xh.z, qb.x, qb.y, qb.z);
      r.w = quantv(xh.w, qb.x, qb.y, qb.z);
      *(float4*)(dst + fi) = r;
    }
  }
}

// ---------------------------------------------------------------- launch
extern "C" void kernel_launch(void* const* d_in, const int* in_sizes, int n_in,
                              void* d_out, int out_size, void* d_ws, size_t ws_size,
                              hipStream_t stream) {
  (void)in_sizes; (void)n_in; (void)out_size; (void)ws_size;
  const float* v   = (const float*)d_in[0];
  const float* Hm  = (const float*)d_in[1];
  const float* ym  = (const float*)d_in[2];
  const float* snr = (const float*)d_in[3];
  const float* gy  = (const float*)d_in[4];
  const float* gH  = (const float*)d_in[5];
  const float* gd  = (const float*)d_in[6];
  const float* W1  = (const float*)d_in[7];
  const float* B1  = (const float*)d_in[8];
  const float* W2  = (const float*)d_in[9];
  const float* B2  = (const float*)d_in[10];
  const float* W3  = (const float*)d_in[11];
  const float* B3  = (const float*)d_in[12];
  const float* Wy  = (const float*)d_in[13];
  const float* By  = (const float*)d_in[14];
  const float* Wh  = (const float*)d_in[15];
  const float* Bh  = (const float*)d_in[16];
  const float* Wd  = (const float*)d_in[17];
  const float* Bd  = (const float*)d_in[18];
  const float* sy  = (const float*)d_in[19];
  const float* sH  = (const float*)d_in[20];
  const float* sd  = (const float*)d_in[21];
  float* out = (float*)d_out;
  float* ws  = (float*)d_ws;

  k_power<<<NBL, 256, 0, stream>>>(Hm, ym, ws);
  k_avg<<<128, 256, 0, stream>>>(ws);
  k_main<<<512, 512, 0, stream>>>(v, Hm, ym, snr, gy, gH, gd,
                                  W1, B1, W2, B2, W3, B3,
                                  Wy, By, Wh, Bh, Wd, Bd,
                                  sy, sH, sd, ws, out);
}

// Round 6
// 70.671 us; speedup vs baseline: 2.5783x; 1.0159x over previous
//
#include <hip/hip_runtime.h>

// Problem constants: B=16, L=1024, K=8, N=64, Hh=64
#define NBL 16384

// workspace float offsets
#define WS_HPOW 0            // [NBL][8]; word0 of each row is reused for j-codes
#define WS_YSUM 131072       // [NBL]
#define WS_AVG  147456       // [B][K]
#define WS_FRAG 147584       // u32[16896] pre-split weight fragment table

// output float offsets
#define OFF_V  0
#define OFF_H  262144
#define OFF_Y  17039360
#define OFF_BT 19136512
#define OFF_BY 19267584
#define OFF_BH 19398656
#define OFF_BD 19529728

typedef short s8v __attribute__((ext_vector_type(8)));
typedef float f32x16 __attribute__((ext_vector_type(16)));
typedef unsigned int u32x4 __attribute__((ext_vector_type(4)));

#define MFMA(a, b, c) __builtin_amdgcn_mfma_f32_32x32x16_bf16(a, b, c, 0, 0, 0)
#define NCALL 22   // 2 (L1) + 8 (L2) + 8 (L3) + 4 (heads)

// ---------------------------------------------------------------- kernel A
__global__ __launch_bounds__(256) void k_power(const float* __restrict__ Hm,
                                               const float* __restrict__ ym,
                                               float* __restrict__ ws) {
  const int bl = blockIdx.x;
  const int t  = threadIdx.x;
  __shared__ float wsum[4][8];
  float4 h4 = *(const float4*)(Hm + bl * 1024 + t * 4);
  float s0 = h4.x * h4.x + h4.y * h4.y;
  float s1 = h4.z * h4.z + h4.w * h4.w;
  #pragma unroll
  for (int m = 4; m <= 32; m <<= 1) {
    s0 += __shfl_xor(s0, m, 64);
    s1 += __shfl_xor(s1, m, 64);
  }
  const int lane = t & 63, w = t >> 6;
  if (lane < 4) {
    wsum[w][2 * lane]     = s0;
    wsum[w][2 * lane + 1] = s1;
  }
  __syncthreads();
  if (t < 8)
    ws[WS_HPOW + bl * 8 + t] = wsum[0][t] + wsum[1][t] + wsum[2][t] + wsum[3][t];
  if (t >= 64 && t < 128) {
    const int u = t - 64;
    float p = 0.0f;
    if (u < 32) {
      float4 v4 = *(const float4*)(ym + bl * 128 + u * 4);
      p = v4.x * v4.x + v4.y * v4.y + v4.z * v4.z + v4.w * v4.w;
    }
    #pragma unroll
    for (int m = 1; m <= 32; m <<= 1) p += __shfl_xor(p, m, 64);
    if (u == 0) ws[WS_YSUM + bl] = p;
  }
}

// ---------------------------------------------------------------- helpers
__device__ __forceinline__ unsigned packbf(float x, float y) {
  return (__float_as_uint(x) >> 16) | (__float_as_uint(y) & 0xFFFF0000u);
}

// exact 3-term truncation split of fp32 (4th term is identically zero)
__device__ __forceinline__ void split3(float x, float& a, float& b, float& c) {
  a = __uint_as_float(__float_as_uint(x) & 0xFFFF0000u);
  const float r1 = x - a;
  b = __uint_as_float(__float_as_uint(r1) & 0xFFFF0000u);
  c = r1 - b;
}

__device__ __forceinline__ void build_frags3(const float* v, s8v* F) {
  float s0[8], s1[8], s2[8];
  #pragma unroll
  for (int e = 0; e < 8; e++) split3(v[e], s0[e], s1[e], s2[e]);
  u32x4 w0, w1, w2;
  w0.x = packbf(s0[0], s0[1]); w0.y = packbf(s0[2], s0[3]);
  w0.z = packbf(s0[4], s0[5]); w0.w = packbf(s0[6], s0[7]);
  w1.x = packbf(s1[0], s1[1]); w1.y = packbf(s1[2], s1[3]);
  w1.z = packbf(s1[4], s1[5]); w1.w = packbf(s1[6], s1[7]);
  w2.x = packbf(s2[0], s2[1]); w2.y = packbf(s2[2], s2[3]);
  w2.z = packbf(s2[4], s2[5]); w2.w = packbf(s2[6], s2[7]);
  F[0] = __builtin_bit_cast(s8v, w0);
  F[1] = __builtin_bit_cast(s8v, w1);
  F[2] = __builtin_bit_cast(s8v, w2);
}

// 8-product emulated-fp32 MAC (bit-identical to R4 mac10, zero terms removed)
__device__ __forceinline__ f32x16 mac8(const s8v* A, const s8v* B, f32x16 c) {
  c = MFMA(A[0], B[0], c);
  c = MFMA(A[0], B[1], c); c = MFMA(A[1], B[0], c);
  c = MFMA(A[0], B[2], c); c = MFMA(A[1], B[1], c); c = MFMA(A[2], B[0], c);
  c = MFMA(A[1], B[2], c); c = MFMA(A[2], B[1], c);
  return c;
}

__device__ __forceinline__ void frag_ld(const u32x4* __restrict__ sFr, int call,
                                        int lane, s8v* F) {
  F[0] = __builtin_bit_cast(s8v, sFr[(call * 3 + 0) * 64 + lane]);
  F[1] = __builtin_bit_cast(s8v, sFr[(call * 3 + 1) * 64 + lane]);
  F[2] = __builtin_bit_cast(s8v, sFr[(call * 3 + 2) * 64 + lane]);
}

// weight element for staging: A[j=32M+(lane&31)][ic=16T+8*(lane>>5)+e]
__device__ __forceinline__ float w_elem(int call, int lane, int e,
                                        const float* __restrict__ W1,
                                        const float* __restrict__ W2,
                                        const float* __restrict__ W3,
                                        const float* __restrict__ Wy,
                                        const float* __restrict__ Wh,
                                        const float* __restrict__ Wd) {
  const int h = lane >> 5, m = lane & 31;
  if (call < 2) {
    const int ic = 8 * h + e;
    return (ic < 9) ? W1[ic * 64 + call * 32 + m] : 0.0f;
  } else if (call < 10) {
    const int idx = call - 2, T = idx >> 1, M = idx & 1;
    return W2[(16 * T + 8 * h + e) * 64 + 32 * M + m];
  } else if (call < 18) {
    const int idx = call - 10, T = idx >> 1, M = idx & 1;
    return W3[(16 * T + 8 * h + e) * 64 + 32 * M + m];
  } else {
    const int ic = 16 * (call - 18) + 8 * h + e;
    if (m < 5)  return Wy[ic * 5 + m];
    if (m < 10) return Wh[ic * 5 + m - 5];
    if (m < 15) return Wd[ic * 5 + m - 10];
    return 0.0f;
  }
}

__device__ __forceinline__ f32x16 cinit(const float* bias, int M, int half) {
  f32x16 c;
  #pragma unroll
  for (int o = 0; o < 4; o++) {
    const float4 b4 = *(const float4*)(bias + M * 32 + o * 8 + 4 * half);
    c[4 * o + 0] = b4.x; c[4 * o + 1] = b4.y;
    c[4 * o + 2] = b4.z; c[4 * o + 3] = b4.w;
  }
  return c;
}

__device__ __forceinline__ f32x16 relu16(f32x16 a) {
  #pragma unroll
  for (int i = 0; i < 16; i++) a[i] = fmaxf(a[i], 0.0f);
  return a;
}

template <int T>
__device__ __forceinline__ void bfragC3(const f32x16& P0, const f32x16& P1,
                                        int half, s8v* F) {
  float v[8];
  #pragma unroll
  for (int m = 0; m < 4; m++) {
    float lo, hi;
    if ((T >> 1) == 0) { lo = P0[8 * (T & 1) + m]; hi = P0[8 * (T & 1) + 4 + m]; }
    else               { lo = P1[8 * (T & 1) + m]; hi = P1[8 * (T & 1) + 4 + m]; }
    const float own  = half ? hi : lo;
    const float send = half ? lo : hi;
    const float recv = __shfl_xor(send, 32, 64);
    v[m]     = half ? recv : own;
    v[4 + m] = half ? own : recv;
  }
  build_frags3(v, F);
}

// compile-time gscale: same IEEE double ops as runtime version, folded
template <int E>   // fsize = 2^E
__device__ __forceinline__ float gscl(int j) {
  constexpr double fs = (double)(1 << E);
  switch (j) {
    case 1:  return (float)(1.0 / sqrt(fs * 7.0));
    case 2:  return (float)(1.0 / sqrt(fs * 127.0));
    case 3:  return (float)(1.0 / sqrt(fs * 2047.0));
    default: return (float)(1.0 / sqrt(fs * 32767.0));
  }
}

template <int E>
__device__ __forceinline__ void qparamsE(int j, const float* __restrict__ sv,
                                         float& se, float& qn, float& qp) {
  se = 1.0f; qn = 0.0f; qp = 0.0f;
  if (j > 0) {
    const int p = 1 << (4 * j - 1);            // 8,128,2048,32768
    const float gs = gscl<E>(j);
    const float s  = sv[j - 1];
    const float sg = s * gs;
    se = sg + (s - sg);                        // literal forward of s_eff
    qn = -(float)p; qp = (float)(p - 1);
  }
}

__device__ __forceinline__ float quantv(float x, float seff, float qn, float qp) {
  float xs = fminf(fmaxf(x / seff, qn), qp);   // exact IEEE div, matches np ref
  float r  = rintf(xs);                        // round half-even == jnp.round
  return (xs + (r - xs)) * seff;
}

// ---------------------------------------------------------------- kernel B
// blocks 0..127: avg_cp reduction; blocks 128..193: pre-split frag table
__global__ __launch_bounds__(256) void k_avg_prep(
    const float* __restrict__ W1, const float* __restrict__ W2,
    const float* __restrict__ W3, const float* __restrict__ Wy,
    const float* __restrict__ Wh, const float* __restrict__ Wd,
    float* __restrict__ ws) {
  const int t = threadIdx.x;
  if (blockIdx.x < 128) {
    const int bk = blockIdx.x;
    const int b = bk >> 3, k = bk & 7;
    __shared__ float red[256];
    float p = 0.0f;
    for (int l = t; l < 1024; l += 256)
      p += ws[WS_HPOW + ((b << 10) + l) * 8 + k];
    red[t] = p;
    __syncthreads();
    for (int st = 128; st > 0; st >>= 1) {
      if (t < st) red[t] += red[t + st];
      __syncthreads();
    }
    if (t == 0) ws[WS_AVG + bk] = red[0] * (1.0f / 1024.0f);
  } else {
    const int i = (blockIdx.x - 128) * 256 + t;     // 0..16895
    const int call = i / 768;
    const int rem  = i - call * 768;
    const int sp   = rem >> 8;
    const int ln   = (rem >> 2) & 63;
    const int wd   = rem & 3;
    const float x0 = w_elem(call, ln, 2 * wd,     W1, W2, W3, Wy, Wh, Wd);
    const float x1 = w_elem(call, ln, 2 * wd + 1, W1, W2, W3, Wy, Wh, Wd);
    float a0, b0, c0, a1, b1, c1;
    split3(x0, a0, b0, c0);
    split3(x1, a1, b1, c1);
    const float lo = (sp == 0) ? a0 : (sp == 1) ? b0 : c0;
    const float hi = (sp == 0) ? a1 : (sp == 1) ? b1 : c1;
    ((unsigned*)ws)[WS_FRAG + i] = packbf(lo, hi);
  }
}

// ---------------------------------------------------------------- kernel C
// wave = 32 sites (4 bl); MLP + decisions + b-links + v_q; codes -> ws
__global__ __launch_bounds__(512, 4) void k_mlp(
    const float* __restrict__ v,  const float* __restrict__ snr,
    const float* __restrict__ gy, const float* __restrict__ gH,
    const float* __restrict__ gd,
    const float* __restrict__ B1, const float* __restrict__ B2,
    const float* __restrict__ B3,
    const float* __restrict__ By, const float* __restrict__ Bh,
    const float* __restrict__ Bd,
    const float* __restrict__ sd,
    float* __restrict__ ws, float* __restrict__ out) {

  __shared__ u32x4 sFr[NCALL * 192];             // 67584 B pre-split A-frags
  __shared__ float sB1v[64], sB2v[64], sB3v[64], sBHv[32];

  const int t = threadIdx.x;
  // ---- stage frag table (coalesced copy from ws; computed once in k_avg_prep)
  {
    const u32x4* gsrc = (const u32x4*)((const unsigned*)ws + WS_FRAG);
    for (int i = t; i < NCALL * 192; i += 512) sFr[i] = gsrc[i];
  }
  if (t < 64) { sB1v[t] = B1[t]; sB2v[t] = B2[t]; sB3v[t] = B3[t]; }
  if (t < 32) sBHv[t] = (t < 5) ? By[t] : (t < 10) ? Bh[t - 5]
                       : (t < 15) ? Bd[t - 10] : 0.0f;
  __syncthreads();

  const int w    = t >> 6;
  const int lane = t & 63;
  const int half = lane >> 5;
  const int site = lane & 31;
  const int bl0  = (blockIdx.x * 8 + w) * 4;   // 4 bl per wave
  const int bl   = bl0 + (site >> 3);
  const int k    = site & 7;

  // ---- features (registers only; half0: f0..f7, half1: f8 + zero pad)
  const float vr = v[bl * 16 + 2 * k], vi = v[bl * 16 + 2 * k + 1];
  s8v Af[3], Bf[3];
  {
    float fv[8];
    if (half == 0) {
      float tot = 0.0f, hp = 0.0f;
      #pragma unroll
      for (int kk = 0; kk < 8; kk++) {
        const float hv = ws[WS_HPOW + bl * 8 + kk];
        tot += hv;
        if (kk == k) hp = hv;
      }
      fv[0] = vr;
      fv[1] = vi;
      fv[2] = snr[bl * 8 + k];
      fv[3] = hp;
      fv[4] = ws[WS_AVG + (bl >> 10) * 8 + k];
      fv[5] = log1pf(hp / (tot - hp + 1e-10f));
      fv[6] = log1pf(tot);
      fv[7] = log1pf(ws[WS_YSUM + bl]);
    } else {
      fv[0] = sqrtf(vr * vr + vi * vi + 1e-10f);
      #pragma unroll
      for (int e = 1; e < 8; e++) fv[e] = 0.0f;
    }
    build_frags3(fv, Bf);
  }

  // ---- layer 1 (K=16)
  f32x16 c0 = cinit(sB1v, 0, half), c1 = cinit(sB1v, 1, half);
  frag_ld(sFr, 0, lane, Af); c0 = mac8(Af, Bf, c0);
  frag_ld(sFr, 1, lane, Af); c1 = mac8(Af, Bf, c1);
  c0 = relu16(c0); c1 = relu16(c1);

  // ---- layer 2 (K=64, 4 ksteps)
  {
    f32x16 n0 = cinit(sB2v, 0, half), n1 = cinit(sB2v, 1, half);
    bfragC3<0>(c0, c1, half, Bf);
    frag_ld(sFr, 2, lane, Af); n0 = mac8(Af, Bf, n0);
    frag_ld(sFr, 3, lane, Af); n1 = mac8(Af, Bf, n1);
    bfragC3<1>(c0, c1, half, Bf);
    frag_ld(sFr, 4, lane, Af); n0 = mac8(Af, Bf, n0);
    frag_ld(sFr, 5, lane, Af); n1 = mac8(Af, Bf, n1);
    bfragC3<2>(c0, c1, half, Bf);
    frag_ld(sFr, 6, lane, Af); n0 = mac8(Af, Bf, n0);
    frag_ld(sFr, 7, lane, Af); n1 = mac8(Af, Bf, n1);
    bfragC3<3>(c0, c1, half, Bf);
    frag_ld(sFr, 8, lane, Af); n0 = mac8(Af, Bf, n0);
    frag_ld(sFr, 9, lane, Af); n1 = mac8(Af, Bf, n1);
    c0 = relu16(n0); c1 = relu16(n1);
  }
  // ---- layer 3
  {
    f32x16 n0 = cinit(sB3v, 0, half), n1 = cinit(sB3v, 1, half);
    bfragC3<0>(c0, c1, half, Bf);
    frag_ld(sFr, 10, lane, Af); n0 = mac8(Af, Bf, n0);
    frag_ld(sFr, 11, lane, Af); n1 = mac8(Af, Bf, n1);
    bfragC3<1>(c0, c1, half, Bf);
    frag_ld(sFr, 12, lane, Af); n0 = mac8(Af, Bf, n0);
    frag_ld(sFr, 13, lane, Af); n1 = mac8(Af, Bf, n1);
    bfragC3<2>(c0, c1, half, Bf);
    frag_ld(sFr, 14, lane, Af); n0 = mac8(Af, Bf, n0);
    frag_ld(sFr, 15, lane, Af); n1 = mac8(Af, Bf, n1);
    bfragC3<3>(c0, c1, half, Bf);
    frag_ld(sFr, 16, lane, Af); n0 = mac8(Af, Bf, n0);
    frag_ld(sFr, 17, lane, Af); n1 = mac8(Af, Bf, n1);
    c0 = relu16(n0); c1 = relu16(n1);
  }
  // ---- heads (M-tile 0 only; rows 15..31 zero)
  f32x16 hc = cinit(sBHv, 0, half);
  {
    bfragC3<0>(c0, c1, half, Bf);
    frag_ld(sFr, 18, lane, Af); hc = mac8(Af, Bf, hc);
    bfragC3<1>(c0, c1, half, Bf);
    frag_ld(sFr, 19, lane, Af); hc = mac8(Af, Bf, hc);
    bfragC3<2>(c0, c1, half, Bf);
    frag_ld(sFr, 20, lane, Af); hc = mac8(Af, Bf, hc);
    bfragC3<3>(c0, c1, half, Bf);
    frag_ld(sFr, 21, lane, Af); hc = mac8(Af, Bf, hc);
  }

  // ---- gather all 16 logits of this lane's site into registers
  float ho[16];
  {
    float hop[8];
    #pragma unroll
    for (int r = 0; r < 8; r++) hop[r] = __shfl_xor(hc[r], 32, 64);
    if (half == 0) {
      #pragma unroll
      for (int r = 0; r < 8; r++) {
        ho[8 * (r >> 2) + (r & 3)]     = hc[r];
        ho[8 * (r >> 2) + 4 + (r & 3)] = hop[r];
      }
    } else {
      #pragma unroll
      for (int r = 0; r < 8; r++) {
        ho[8 * (r >> 2) + 4 + (r & 3)] = hc[r];
        ho[8 * (r >> 2) + (r & 3)]     = hop[r];
      }
    }
  }

  // ---- decisions (all lanes redundant; exact R5 math)
  int bjH, bjD, bjY;
  {
    const float* gg = gH + (bl0 * 8 + site) * 5;
    float bv = ho[5] + gg[0]; int bj = 0;
    #pragma unroll
    for (int c = 1; c < 5; c++) {
      const float lv = ho[5 + c] + gg[c];
      if (lv > bv) { bv = lv; bj = c; }
    }
    bjH = bj;
  }
  {
    const float* gg = gd + (bl0 * 8 + site) * 5;
    float bv = ho[10] + gg[0]; int bj = 0;
    #pragma unroll
    for (int c = 1; c < 5; c++) {
      const float lv = ho[10 + c] + gg[c];
      if (lv > bv) { bv = lv; bj = c; }
    }
    bjD = bj;
  }
  {
    const int gb = lane & 24;
    const float* gg = gy + bl * 5;
    float bv = 0.0f; int bj = 0;
    #pragma unroll
    for (int c = 0; c < 5; c++) {
      float acc = 0.0f;
      #pragma unroll
      for (int kk = 0; kk < 8; kk++) acc += __shfl(ho[c], gb + kk, 64);
      const float lv = acc * 0.125f + gg[c];
      if (c == 0 || lv > bv) { bv = lv; bj = c; }
    }
    bjY = bj;
  }

  // ---- pack H j-codes (3b x 8) + y j-code (3b at bit 27) per bl
  unsigned cH = 0;
  #pragma unroll
  for (int kk = 0; kk < 8; kk++)
    cH |= ((unsigned)__shfl(bjH, (lane & 24) + kk, 64)) << (3 * kk);
  cH |= ((unsigned)bjY) << 27;

  if (lane < 32) {
    if ((site & 7) == 0)
      ((unsigned*)ws)[WS_HPOW + bl * 8] = cH;   // own slot, already consumed
    {   // b-links
      const int oi = bl0 * 8 + site;
      const float by_ = 64.0f  * (float)bjY;
      const float bH_ = 512.0f * (float)bjH;
      const float bd_ = 8.0f   * (float)bjD;
      out[OFF_BT + oi] = by_ + bH_ + bd_;
      out[OFF_BY + oi] = by_;
      out[OFF_BH + oi] = bH_;
      out[OFF_BD + oi] = bd_;
    }
    {   // v_q
      float dse, dqn, dqp;
      qparamsE<18>(bjD, sd, dse, dqn, dqp);
      float2 r;
      r.x = quantv(vr, dse, dqn, dqp);
      r.y = quantv(vi, dse, dqn, dqp);
      *(float2*)(out + OFF_V + bl0 * 16 + site * 2) = r;
    }
  }
}

// ---------------------------------------------------------------- kernel D
// pure streaming quant: one wave per bl; H row (4 KB) + y row (512 B)
__global__ __launch_bounds__(256) void k_hq(const float* __restrict__ Hm,
                                            const float* __restrict__ ym,
                                            const float* __restrict__ sy,
                                            const float* __restrict__ sH,
                                            const float* __restrict__ ws,
                                            float* __restrict__ out) {
  const int t    = threadIdx.x;
  const int lane = t & 63;
  const int bl   = blockIdx.x * 4 + (t >> 6);

  const unsigned code = ((const unsigned*)ws)[WS_HPOW + bl * 8];
  const int k0 = (2 * lane) & 7;
  const int jA = (code >> (3 * k0)) & 7;
  const int jB = (code >> (3 * (k0 + 1))) & 7;
  const int jY = (code >> 27) & 7;

  float ase, aqn, aqp, bse, bqn, bqp, yse, yqn, yqp;
  qparamsE<24>(jA, sH, ase, aqn, aqp);
  qparamsE<24>(jB, sH, bse, bqn, bqp);
  qparamsE<21>(jY, sy, yse, yqn, yqp);

  // ---- y_q: 32 float4 per bl
  if (lane < 32) {
    const int gi = bl * 128 + lane * 4;
    const float4 xv = *(const float4*)(ym + gi);
    float4 r;
    r.x = quantv(xv.x, yse, yqn, yqp);
    r.y = quantv(xv.y, yse, yqn, yqp);
    r.z = quantv(xv.z, yse, yqn, yqp);
    r.w = quantv(xv.w, yse, yqn, yqp);
    *(float4*)(out + OFF_Y + gi) = r;
  }

  // ---- H_q: 256 float4 per bl, coalesced
  const float* src = Hm + bl * 1024;
  float* dst = out + OFF_H + bl * 1024;
  #pragma unroll
  for (int c = 0; c < 4; c++) {
    const int fi = (c * 64 + lane) * 4;
    const float4 xh = *(const float4*)(src + fi);
    float4 r;
    r.x = quantv(xh.x, ase, aqn, aqp);
    r.y = quantv(xh.y, ase, aqn, aqp);
    r.z = quantv(xh.z, bse, bqn, bqp);
    r.w = quantv(xh.w, bse, bqn, bqp);
    *(float4*)(dst + fi) = r;
  }
}

// ---------------------------------------------------------------- launch
extern "C" void kernel_launch(void* const* d_in, const int* in_sizes, int n_in,
                              void* d_out, int out_size, void* d_ws, size_t ws_size,
                              hipStream_t stream) {
  (void)in_sizes; (void)n_in; (void)out_size; (void)ws_size;
  const float* v   = (const float*)d_in[0];
  const float* Hm  = (const float*)d_in[1];
  const float* ym  = (const float*)d_in[2];
  const float* snr = (const float*)d_in[3];
  const float* gy  = (const float*)d_in[4];
  const float* gH  = (const float*)d_in[5];
  const float* gd  = (const float*)d_in[6];
  const float* W1  = (const float*)d_in[7];
  const float* B1  = (const float*)d_in[8];
  const float* W2  = (const float*)d_in[9];
  const float* B2  = (const float*)d_in[10];
  const float* W3  = (const float*)d_in[11];
  const float* B3  = (const float*)d_in[12];
  const float* Wy  = (const float*)d_in[13];
  const float* By  = (const float*)d_in[14];
  const float* Wh  = (const float*)d_in[15];
  const float* Bh  = (const float*)d_in[16];
  const float* Wd  = (const float*)d_in[17];
  const float* Bd  = (const float*)d_in[18];
  const float* sy  = (const float*)d_in[19];
  const float* sH  = (const float*)d_in[20];
  const float* sd  = (const float*)d_in[21];
  float* out = (float*)d_out;
  float* ws  = (float*)d_ws;

  k_power<<<NBL, 256, 0, stream>>>(Hm, ym, ws);
  k_avg_prep<<<194, 256, 0, stream>>>(W1, W2, W3, Wy, Wh, Wd, ws);
  k_mlp<<<512, 512, 0, stream>>>(v, snr, gy, gH, gd,
                                 B1, B2, B3, By, Bh, Bd, sd, ws, out);
  k_hq<<<4096, 256, 0, stream>>>(Hm, ym, sy, sH, ws, out);
}